// Round 14
// baseline (91.517 us; speedup 1.0000x reference)
//
#include <hip/hip_runtime.h>

#define N_NODES 50001
#define DIM 128
#define GEMM_BLOCKS 782                // ceil(N_NODES / 64): 4 waves x 16 rows per block
#define CAP 64                         // slot capacity per node
#define NB 196                         // buckets = dst>>8
#define FILLB 293                      // fill blocks
#define EPB 2048                       // edges per fill block (293*2048 >= 600000)
#define BCAP 40                        // per-(block,bucket) LDS capacity (mean 10.45)
#define GCAPR 640                      // per-(bucket,replica) capacity (mean 383, +13 sigma)
#define OCAP 8192                      // overflow list capacity
#define ZDEG 49                        // prep blocks zeroing deg (12501 uint4)
#define ZG 25                          // prep blocks zeroing gcntp (6272 uint4)

typedef __attribute__((ext_vector_type(8))) short short8v;   // 8 bf16 (MFMA A/B frag)
typedef __attribute__((ext_vector_type(4))) float f32x4;     // MFMA C/D frag

__device__ __forceinline__ ushort f2bf(float f) {
    unsigned u = __float_as_uint(f);
    unsigned r = (u + 0x7FFF + ((u >> 16) & 1)) >> 16;   // round-to-nearest-even
    return (ushort)r;
}

// ------- prep: [zero deg | zero gcntp/ocnt | transpose W (fp32) -> wt (bf16 [n][k])] ------
__global__ void prep_kernel(int* __restrict__ deg, int* __restrict__ gcntp,
                            int* __restrict__ ocnt,
                            const float* __restrict__ Wg, ushort* __restrict__ wt) {
    __shared__ float tile[32][36];
    const int t = threadIdx.x;
    if (blockIdx.x < ZDEG) {
        int i = blockIdx.x * 256 + t;
        if (i < 12501) ((uint4*)deg)[i] = make_uint4(0, 0, 0, 0);
        return;
    }
    if (blockIdx.x < ZDEG + ZG) {
        int i = (blockIdx.x - ZDEG) * 256 + t;
        if (i < 6272) ((uint4*)gcntp)[i] = make_uint4(0, 0, 0, 0);
        if (blockIdx.x == ZDEG && t == 0) *ocnt = 0;
        return;
    }
    const int b2 = blockIdx.x - (ZDEG + ZG);   // 0..15
    const int bk = b2 >> 2;               // k-tile
    const int bn = b2 & 3;                // n-tile
    {
        int k = bk * 32 + (t >> 3);
        int n = bn * 32 + (t & 7) * 4;
        float4 v = *(const float4*)&Wg[(size_t)k * DIM + n];
        tile[t >> 3][(t & 7) * 4 + 0] = v.x;
        tile[t >> 3][(t & 7) * 4 + 1] = v.y;
        tile[t >> 3][(t & 7) * 4 + 2] = v.z;
        tile[t >> 3][(t & 7) * 4 + 3] = v.w;
    }
    __syncthreads();
    {
        int n = bn * 32 + (t >> 3);
        int k = bk * 32 + (t & 7) * 4;
        ushort4 w4;
        w4.x = f2bf(tile[(t & 7) * 4 + 0][t >> 3]);
        w4.y = f2bf(tile[(t & 7) * 4 + 1][t >> 3]);
        w4.z = f2bf(tile[(t & 7) * 4 + 2][t >> 3]);
        w4.w = f2bf(tile[(t & 7) * 4 + 3][t >> 3]);
        *(ushort4*)&wt[(size_t)n * DIM + k] = w4;
    }
}

// -------- fused: [MFMA gemm (first) | level-1: deg histogram + LDS bin -> replica flush] --
// entry = src | (dst&255)<<16 (| bucket<<24 in overflow list).
__launch_bounds__(256)
__global__ void gemm_fill_kernel(const float* __restrict__ X, const ushort* __restrict__ wt,
                                 ushort* __restrict__ h16,
                                 const int* __restrict__ src, const int* __restrict__ dst,
                                 int E, int* __restrict__ deg,
                                 int* __restrict__ gcntp, int* __restrict__ gbkt,
                                 int* __restrict__ ocnt, int* __restrict__ obkt) {
    __shared__ int lcnt[NB];
    __shared__ int lbkt[NB * BCAP];      // ~31 KB
    const int bid = blockIdx.x;
    const int t   = threadIdx.x;
    if (bid >= GEMM_BLOCKS) {
        const int fid = bid - GEMM_BLOCKS;
        const int r   = bid & 7;         // ~XCD id (round-robin dispatch heuristic)
        for (int i = t; i < NB; i += 256) lcnt[i] = 0;
        __syncthreads();
        const int e0 = fid * EPB;
        const int e1 = min(e0 + EPB, E);
        for (int e = e0 + t; e < e1; e += 256) {
            int d = dst[e];
            int s = src[e];
            int b = d >> 8;
            unsigned en = (unsigned)s | ((unsigned)(d & 255) << 16);
            atomicAdd(&deg[d], 1);                    // global degree histogram
            int pos = atomicAdd(&lcnt[b], 1);
            if (pos < BCAP) lbkt[b * BCAP + pos] = (int)en;
            else {
                int op = atomicAdd(ocnt, 1);
                if (op < OCAP) obkt[op] = (int)(en | ((unsigned)b << 24));
            }
        }
        __syncthreads();
        if (t < NB) {
            int c = min(lcnt[t], BCAP);
            if (c > 0) {
                int gpos = atomicAdd(&gcntp[(t * 8 + r) * 16], c);
                int* gp = &gbkt[(size_t)(t * 8 + r) * GCAPR];
                for (int i = 0; i < c; ++i) {
                    int g = gpos + i;
                    if (g < GCAPR) gp[g] = lbkt[t * BCAP + i];
                    else {
                        int op = atomicAdd(ocnt, 1);
                        if (op < OCAP)
                            obkt[op] = (int)((unsigned)lbkt[t * BCAP + i] | ((unsigned)t << 24));
                    }
                }
            }
        }
        return;
    }
    const int vb   = bid;
    const int l    = t & 63;
    const int wave = t >> 6;
    const int m0   = vb * 64 + wave * 16;
    const int lm   = l & 15;          // A row / D col index
    const int lg   = l >> 4;          // k-group

    const int arow  = m0 + lm;
    const bool aok  = (arow > 0) && (arow < N_NODES);   // row 0 forced to zero
    const int koff0 = lg * 8;

    f32x4 acc[8];
#pragma unroll
    for (int ct = 0; ct < 8; ++ct) acc[ct] = (f32x4){0.f, 0.f, 0.f, 0.f};

#pragma unroll
    for (int kci = 0; kci < 4; ++kci) {
        const int kc = kci * 32;
        // A frag: X[arow][kc + koff0 + 0..7] fp32 -> bf16 (same (g,j)->k bijection as B)
        float4 v0 = make_float4(0.f, 0.f, 0.f, 0.f), v1 = v0;
        if (aok) {
            const float* xp = &X[(size_t)arow * DIM + kc + koff0];
            v0 = *(const float4*)xp;
            v1 = *(const float4*)(xp + 4);
        }
        short8v a;
        a[0] = (short)f2bf(v0.x); a[1] = (short)f2bf(v0.y);
        a[2] = (short)f2bf(v0.z); a[3] = (short)f2bf(v0.w);
        a[4] = (short)f2bf(v1.x); a[5] = (short)f2bf(v1.y);
        a[6] = (short)f2bf(v1.z); a[7] = (short)f2bf(v1.w);
#pragma unroll
        for (int ct = 0; ct < 8; ++ct) {
            short8v b = *(const short8v*)&wt[(size_t)(ct * 16 + lm) * DIM + kc + koff0];
            acc[ct] = __builtin_amdgcn_mfma_f32_16x16x32_bf16(a, b, acc[ct], 0, 0, 0);
        }
    }

    // D: row = m0 + lg*4 + r, col = ct*16 + lm
#pragma unroll
    for (int r = 0; r < 4; ++r) {
        int row = m0 + lg * 4 + r;
        if (row < N_NODES) {
            ushort* hp = &h16[(size_t)row * DIM + lm];
#pragma unroll
            for (int ct = 0; ct < 8; ++ct) hp[ct * 16] = f2bf(acc[ct][r]);
        }
    }
}

// ------- fused level-2 + pull: bucket-quarter LDS binning, then pull from LDS lists -------
// block b: bucket B=b>>2, quarter q=b&3 -> nodes [B*256+q*64, +64).
// out[n] = dis_n*(sum_e dis_s*h[s] + dis_n*h[n]) + bias
__launch_bounds__(256)
__global__ void binpull_kernel(const int* __restrict__ gcntp, const int* __restrict__ gbkt,
                               const int* __restrict__ ocnt, const int* __restrict__ obkt,
                               const int* __restrict__ deg, const ushort* __restrict__ h16,
                               const float* __restrict__ bias, float* __restrict__ out) {
    __shared__ __align__(16) ushort lslot[64 * CAP];   // 8 KB
    __shared__ int lcnt[64];
    const int t = threadIdx.x;
    const int B = blockIdx.x >> 2;
    const int q = blockIdx.x & 3;
    if (t < 64) lcnt[t] = 0;
    __syncthreads();

    // phase 1: filter bucket B's sub-lists to our 64-node quarter, bin into LDS
    for (int r = 0; r < 8; ++r) {
        const int cnt = min(gcntp[(B * 8 + r) * 16], GCAPR);
        const int* bp = &gbkt[(size_t)(B * 8 + r) * GCAPR];
        for (int i = t; i < cnt; i += 256) {
            unsigned en = (unsigned)bp[i];
            int dlow = (en >> 16) & 255;
            if ((dlow >> 6) == q) {
                int ln = dlow & 63;
                int pos = atomicAdd(&lcnt[ln], 1);
                if (pos < CAP) lslot[ln * CAP + pos] = (ushort)(en & 0xFFFFu);
            }
        }
    }
    const int oc = min(*ocnt, OCAP);
    for (int i = t; i < oc; i += 256) {
        unsigned en = (unsigned)obkt[i];
        if ((int)(en >> 24) == B) {
            int dlow = (en >> 16) & 255;
            if ((dlow >> 6) == q) {
                int ln = dlow & 63;
                int pos = atomicAdd(&lcnt[ln], 1);
                if (pos < CAP) lslot[ln * CAP + pos] = (ushort)(en & 0xFFFFu);
            }
        }
    }
    __syncthreads();

    // phase 2: pull. wave w handles ln = w, w+4, ... ; quarter-wave per edge slot.
    const int lane = t & 63;
    const int w    = t >> 6;
    const int g    = lane >> 4;     // edge slot group 0..3
    const int c    = lane & 15;     // col slot: bf16 cols c*8 .. c*8+7

    for (int ln = w; ln < 64; ln += 4) {
        const int n = B * 256 + q * 64 + ln;
        if (n >= N_NODES) break;            // wave-uniform

        const int dn_i = lcnt[ln];          // true in-degree of n
        const int end  = min(dn_i, CAP);
        const ushort* sp = &lslot[ln * CAP];

        float ac[8];
#pragma unroll
        for (int j = 0; j < 8; ++j) ac[j] = 0.f;

        int e = g;
        while (e + 4 < end) {               // 2 edges per group per iter
            int s0 = sp[e];
            int s1 = sp[e + 4];
            float d0 = rsqrtf(1.0f + (float)deg[s0]);
            float d1 = rsqrtf(1.0f + (float)deg[s1]);
            uint4 u0 = *(const uint4*)&h16[(size_t)s0 * DIM + c * 8];
            uint4 u1 = *(const uint4*)&h16[(size_t)s1 * DIM + c * 8];
            const unsigned w0[4] = {u0.x, u0.y, u0.z, u0.w};
            const unsigned w1[4] = {u1.x, u1.y, u1.z, u1.w};
#pragma unroll
            for (int p = 0; p < 4; ++p) {
                ac[2*p]   += d0 * __uint_as_float(w0[p] << 16)
                           + d1 * __uint_as_float(w1[p] << 16);
                ac[2*p+1] += d0 * __uint_as_float(w0[p] & 0xFFFF0000u)
                           + d1 * __uint_as_float(w1[p] & 0xFFFF0000u);
            }
            e += 8;
        }
        while (e < end) {
            int s = sp[e];
            float d = rsqrtf(1.0f + (float)deg[s]);
            uint4 u = *(const uint4*)&h16[(size_t)s * DIM + c * 8];
            const unsigned wv[4] = {u.x, u.y, u.z, u.w};
#pragma unroll
            for (int p = 0; p < 4; ++p) {
                ac[2*p]   += d * __uint_as_float(wv[p] << 16);
                ac[2*p+1] += d * __uint_as_float(wv[p] & 0xFFFF0000u);
            }
            e += 4;
        }

        // combine the 4 edge-slot partials (same cols in every group)
#pragma unroll
        for (int j = 0; j < 8; ++j) {
            ac[j] += __shfl_xor(ac[j], 16, 64);
            ac[j] += __shfl_xor(ac[j], 32, 64);
        }

        if (g == 0) {
            const float dn = rsqrtf(1.0f + (float)dn_i);
            uint4 us = *(const uint4*)&h16[(size_t)n * DIM + c * 8];   // self row (bf16)
            const unsigned wsr[4] = {us.x, us.y, us.z, us.w};
            float r[8];
#pragma unroll
            for (int p = 0; p < 4; ++p) {
                r[2*p]   = ac[2*p]   + dn * __uint_as_float(wsr[p] << 16);
                r[2*p+1] = ac[2*p+1] + dn * __uint_as_float(wsr[p] & 0xFFFF0000u);
            }
            float* op = &out[(size_t)n * DIM + c * 8];
            const float* bp = &bias[c * 8];
            float4 o0, o1;
            o0.x = dn * r[0] + bp[0]; o0.y = dn * r[1] + bp[1];
            o0.z = dn * r[2] + bp[2]; o0.w = dn * r[3] + bp[3];
            o1.x = dn * r[4] + bp[4]; o1.y = dn * r[5] + bp[5];
            o1.z = dn * r[6] + bp[6]; o1.w = dn * r[7] + bp[7];
            *(float4*)op = o0;
            *(float4*)(op + 4) = o1;
        }
    }
}

extern "C" void kernel_launch(void* const* d_in, const int* in_sizes, int n_in,
                              void* d_out, int out_size, void* d_ws, size_t ws_size,
                              hipStream_t stream) {
    const float* W_embed = (const float*)d_in[0];
    const float* W_gcn   = (const float*)d_in[1];
    const float* b_gcn   = (const float*)d_in[2];
    const int*   edges   = (const int*)d_in[3];
    const int E = in_sizes[3] / 2;
    const int* src = edges;
    const int* dst = edges + E;

    float* out = (float*)d_out;
    char*  ws  = (char*)d_ws;
    int*    gcntp = (int*)ws;                    // NB*8*16 ints (100 KB)  @ 0
    int*    ocnt  = (int*)(ws + 0x19000);        // 1 int                  @ 100 KB
    int*    obkt  = (int*)(ws + 0x20000);        // OCAP ints (32 KB)      @ 128 KB
    ushort* wt    = (ushort*)(ws + 0x28000);     // 128x128 bf16 (32 KB)   @ 160 KB
    int*    gbkt  = (int*)(ws + 0x30000);        // NB*8*GCAPR ints (4 MB) @ 192 KB
    int*    deg   = (int*)(ws + 0x500000);       // 50004 ints (200 KB)    @ 5 MB
    ushort* h16   = (ushort*)(ws + 0x600000);    // N*D bf16 (12.8 MB)     @ 6 MB

    prep_kernel<<<ZDEG + ZG + 16, 256, 0, stream>>>(deg, gcntp, ocnt, W_gcn, wt);
    gemm_fill_kernel<<<GEMM_BLOCKS + FILLB, 256, 0, stream>>>(
        W_embed, wt, h16, src, dst, E, deg, gcntp, gbkt, ocnt, obkt);
    binpull_kernel<<<NB * 4, 256, 0, stream>>>(gcntp, gbkt, ocnt, obkt, deg, h16, b_gcn, out);
}

// Round 15
// 71.451 us; speedup vs baseline: 1.2808x; 1.2808x over previous
//
#include <hip/hip_runtime.h>

#define N_NODES 50001
#define DIM 128
#define GEMM_BLOCKS 782                // ceil(N_NODES / 64): 4 waves x 16 rows per block
#define CAP 64                         // slot capacity per node
#define NB 196                         // buckets = dst>>8
#define FILLB 488                      // fill blocks
#define EPB 1232                       // edges per fill block (488*1232 = 601216 >= 600000)
#define BCAP 24                        // per-(block,bucket) LDS capacity (mean 6.3)
#define GCAPR 640                      // per-(bucket,replica) capacity (mean 383, +13 sigma)
#define OCAP 8192                      // overflow list capacity

typedef __attribute__((ext_vector_type(8))) short short8v;   // 8 bf16 (MFMA A/B frag)
typedef __attribute__((ext_vector_type(4))) float f32x4;     // MFMA C/D frag

__device__ __forceinline__ ushort f2bf(float f) {
    unsigned u = __float_as_uint(f);
    unsigned r = (u + 0x7FFF + ((u >> 16) & 1)) >> 16;   // round-to-nearest-even
    return (ushort)r;
}

// ---------------- prep: [zero counters | transpose W (fp32) -> wt (bf16 [n][k])] ----------
__global__ void prep_kernel(int* __restrict__ gcntp, int* __restrict__ ocnt,
                            const float* __restrict__ Wg, ushort* __restrict__ wt) {
    __shared__ float tile[32][36];
    const int t = threadIdx.x;
    if (blockIdx.x == 0) {
        for (int i = t; i < NB * 8 * 16; i += 256) gcntp[i] = 0;
        if (t == 0) *ocnt = 0;
        return;
    }
    const int b2 = blockIdx.x - 1;        // 0..15
    const int bk = b2 >> 2;               // k-tile
    const int bn = b2 & 3;                // n-tile
    {
        int k = bk * 32 + (t >> 3);
        int n = bn * 32 + (t & 7) * 4;
        float4 v = *(const float4*)&Wg[(size_t)k * DIM + n];
        tile[t >> 3][(t & 7) * 4 + 0] = v.x;
        tile[t >> 3][(t & 7) * 4 + 1] = v.y;
        tile[t >> 3][(t & 7) * 4 + 2] = v.z;
        tile[t >> 3][(t & 7) * 4 + 3] = v.w;
    }
    __syncthreads();
    {
        int n = bn * 32 + (t >> 3);
        int k = bk * 32 + (t & 7) * 4;
        ushort4 w4;
        w4.x = f2bf(tile[(t & 7) * 4 + 0][t >> 3]);
        w4.y = f2bf(tile[(t & 7) * 4 + 1][t >> 3]);
        w4.z = f2bf(tile[(t & 7) * 4 + 2][t >> 3]);
        w4.w = f2bf(tile[(t & 7) * 4 + 3][t >> 3]);
        *(ushort4*)&wt[(size_t)n * DIM + k] = w4;
    }
}

// -------- fused: [MFMA gemm (first) | level-1: LDS bin 1232 edges -> parallel flush] ------
// entry = src | (dst&255)<<16 (| bucket<<24 in overflow list).
__launch_bounds__(256)
__global__ void gemm_fill_kernel(const float* __restrict__ X, const ushort* __restrict__ wt,
                                 ushort* __restrict__ h16,
                                 const int* __restrict__ src, const int* __restrict__ dst,
                                 int E, int* __restrict__ gcntp, int* __restrict__ gbkt,
                                 int* __restrict__ ocnt, int* __restrict__ obkt) {
    __shared__ int lcnt[NB];
    __shared__ int lgpos[NB];
    __shared__ int lbkt[NB * BCAP];      // ~18.4 KB (20.4 KB total LDS)
    const int bid = blockIdx.x;
    const int t   = threadIdx.x;
    if (bid >= GEMM_BLOCKS) {
        const int fid = bid - GEMM_BLOCKS;
        const int r   = bid & 7;         // ~XCD id (round-robin dispatch heuristic)
        for (int i = t; i < NB; i += 256) lcnt[i] = 0;
        __syncthreads();
        const int e0 = fid * EPB;
        const int e1 = min(e0 + EPB, E);
        for (int e = e0 + t; e < e1; e += 256) {
            int d = dst[e];
            int s = src[e];
            int b = d >> 8;
            unsigned en = (unsigned)s | ((unsigned)(d & 255) << 16);
            int pos = atomicAdd(&lcnt[b], 1);
            if (pos < BCAP) lbkt[b * BCAP + pos] = (int)en;
            else {
                int op = atomicAdd(ocnt, 1);
                if (op < OCAP) obkt[op] = (int)(en | ((unsigned)b << 24));
            }
        }
        __syncthreads();
        // flush phase A: one replica atomic per bucket, broadcast base via LDS
        if (t < NB) {
            int c = min(lcnt[t], BCAP);
            lcnt[t] = c;
            lgpos[t] = (c > 0) ? atomicAdd(&gcntp[(t * 8 + r) * 16], c) : 0;
        }
        __syncthreads();
        // flush phase B: 4 threads per bucket copy interleaved elements
#pragma unroll
        for (int rr = 0; rr < 4; ++rr) {
            int b = rr * 64 + (t >> 2);
            if (b < NB) {
                const int j    = t & 3;
                const int c    = lcnt[b];
                const int gpos = lgpos[b];
                int* gp = &gbkt[(size_t)(b * 8 + r) * GCAPR];
                for (int i = j; i < c; i += 4) {
                    int g = gpos + i;
                    if (g < GCAPR) gp[g] = lbkt[b * BCAP + i];
                    else {
                        int op = atomicAdd(ocnt, 1);
                        if (op < OCAP)
                            obkt[op] = (int)((unsigned)lbkt[b * BCAP + i] | ((unsigned)b << 24));
                    }
                }
            }
        }
        return;
    }
    const int vb   = bid;
    const int l    = t & 63;
    const int wave = t >> 6;
    const int m0   = vb * 64 + wave * 16;
    const int lm   = l & 15;          // A row / D col index
    const int lg   = l >> 4;          // k-group

    const int arow  = m0 + lm;
    const bool aok  = (arow > 0) && (arow < N_NODES);   // row 0 forced to zero
    const int koff0 = lg * 8;

    f32x4 acc[8];
#pragma unroll
    for (int ct = 0; ct < 8; ++ct) acc[ct] = (f32x4){0.f, 0.f, 0.f, 0.f};

#pragma unroll
    for (int kci = 0; kci < 4; ++kci) {
        const int kc = kci * 32;
        // A frag: X[arow][kc + koff0 + 0..7] fp32 -> bf16 (same (g,j)->k bijection as B)
        float4 v0 = make_float4(0.f, 0.f, 0.f, 0.f), v1 = v0;
        if (aok) {
            const float* xp = &X[(size_t)arow * DIM + kc + koff0];
            v0 = *(const float4*)xp;
            v1 = *(const float4*)(xp + 4);
        }
        short8v a;
        a[0] = (short)f2bf(v0.x); a[1] = (short)f2bf(v0.y);
        a[2] = (short)f2bf(v0.z); a[3] = (short)f2bf(v0.w);
        a[4] = (short)f2bf(v1.x); a[5] = (short)f2bf(v1.y);
        a[6] = (short)f2bf(v1.z); a[7] = (short)f2bf(v1.w);
#pragma unroll
        for (int ct = 0; ct < 8; ++ct) {
            short8v b = *(const short8v*)&wt[(size_t)(ct * 16 + lm) * DIM + kc + koff0];
            acc[ct] = __builtin_amdgcn_mfma_f32_16x16x32_bf16(a, b, acc[ct], 0, 0, 0);
        }
    }

    // D: row = m0 + lg*4 + r, col = ct*16 + lm
#pragma unroll
    for (int r = 0; r < 4; ++r) {
        int row = m0 + lg * 4 + r;
        if (row < N_NODES) {
            ushort* hp = &h16[(size_t)row * DIM + lm];
#pragma unroll
            for (int ct = 0; ct < 8; ++ct) hp[ct * 16] = f2bf(acc[ct][r]);
        }
    }
}

// ---------------- level-2: per-bucket LDS binning -> slot rows + deg (all streaming) ------
__launch_bounds__(256)
__global__ void bin_kernel(const int* __restrict__ gcntp, const int* __restrict__ gbkt,
                           const int* __restrict__ ocnt, const int* __restrict__ obkt,
                           ushort* __restrict__ slot, int* __restrict__ deg) {
    __shared__ __align__(16) ushort lslot[256 * CAP];   // 32 KB
    __shared__ int ldeg[256];
    const int t = threadIdx.x;
    const int b = blockIdx.x;
    ldeg[t] = 0;
    __syncthreads();

    for (int r = 0; r < 8; ++r) {
        const int cnt = min(gcntp[(b * 8 + r) * 16], GCAPR);
        const int* bp = &gbkt[(size_t)(b * 8 + r) * GCAPR];
        for (int i = t; i < cnt; i += 256) {
            unsigned en = (unsigned)bp[i];
            int dlow = (en >> 16) & 255;
            int pos = atomicAdd(&ldeg[dlow], 1);
            if (pos < CAP) lslot[dlow * CAP + pos] = (ushort)(en & 0xFFFFu);
        }
    }
    const int oc = min(*ocnt, OCAP);
    for (int i = t; i < oc; i += 256) {
        unsigned en = (unsigned)obkt[i];
        if ((int)(en >> 24) == b) {
            int dlow = (en >> 16) & 255;
            int pos = atomicAdd(&ldeg[dlow], 1);
            if (pos < CAP) lslot[dlow * CAP + pos] = (ushort)(en & 0xFFFFu);
        }
    }
    __syncthreads();

    const int node = b * 256 + t;
    if (node < N_NODES) deg[node] = ldeg[t];
    // stream 32 KB of slot rows (tails beyond ldeg are never read)
    const uint4* ls4 = (const uint4*)lslot;
    uint4* gs4 = (uint4*)&slot[(size_t)b * 256 * CAP];
#pragma unroll
    for (int k = 0; k < 8; ++k) gs4[k * 256 + t] = ls4[k * 256 + t];
}

// ---------------- pull: out[n] = dis_n*(sum_e dis_s*h[s] + dis_n*h[n]) + b ----------
// One wave per node; quarter-wave (16 lanes x 16B) per edge -> 4 edges in flight.
__launch_bounds__(256)
__global__ void pull_kernel(const int* __restrict__ deg, const ushort* __restrict__ slot,
                            const ushort* __restrict__ h16,
                            const float* __restrict__ b, float* __restrict__ out) {
    const int tid  = threadIdx.x;
    const int lane = tid & 63;
    const int g    = lane >> 4;     // edge slot group 0..3
    const int c    = lane & 15;     // col slot: bf16 cols c*8 .. c*8+7
    const int n    = blockIdx.x * 4 + (tid >> 6);
    if (n >= N_NODES) return;

    const int dn_i = deg[n];
    const int end  = min(dn_i, CAP);
    const ushort* sp = &slot[(size_t)n * CAP];

    float ac[8];
#pragma unroll
    for (int j = 0; j < 8; ++j) ac[j] = 0.f;

    int e = g;
    while (e + 4 < end) {           // 2 edges per group per iter
        int s0 = sp[e];
        int s1 = sp[e + 4];
        float d0 = rsqrtf(1.0f + (float)deg[s0]);
        float d1 = rsqrtf(1.0f + (float)deg[s1]);
        uint4 u0 = *(const uint4*)&h16[(size_t)s0 * DIM + c * 8];
        uint4 u1 = *(const uint4*)&h16[(size_t)s1 * DIM + c * 8];
        const unsigned w0[4] = {u0.x, u0.y, u0.z, u0.w};
        const unsigned w1[4] = {u1.x, u1.y, u1.z, u1.w};
#pragma unroll
        for (int p = 0; p < 4; ++p) {
            ac[2*p]   += d0 * __uint_as_float(w0[p] << 16)
                       + d1 * __uint_as_float(w1[p] << 16);
            ac[2*p+1] += d0 * __uint_as_float(w0[p] & 0xFFFF0000u)
                       + d1 * __uint_as_float(w1[p] & 0xFFFF0000u);
        }
        e += 8;
    }
    while (e < end) {
        int s = sp[e];
        float d = rsqrtf(1.0f + (float)deg[s]);
        uint4 u = *(const uint4*)&h16[(size_t)s * DIM + c * 8];
        const unsigned w[4] = {u.x, u.y, u.z, u.w};
#pragma unroll
        for (int p = 0; p < 4; ++p) {
            ac[2*p]   += d * __uint_as_float(w[p] << 16);
            ac[2*p+1] += d * __uint_as_float(w[p] & 0xFFFF0000u);
        }
        e += 4;
    }

    // combine the 4 edge-slot partials (same cols in every group)
#pragma unroll
    for (int j = 0; j < 8; ++j) {
        ac[j] += __shfl_xor(ac[j], 16, 64);
        ac[j] += __shfl_xor(ac[j], 32, 64);
    }

    if (g == 0) {
        const float dn = rsqrtf(1.0f + (float)dn_i);
        uint4 us = *(const uint4*)&h16[(size_t)n * DIM + c * 8];   // self row (bf16)
        const unsigned ws[4] = {us.x, us.y, us.z, us.w};
        float r[8];
#pragma unroll
        for (int p = 0; p < 4; ++p) {
            r[2*p]   = ac[2*p]   + dn * __uint_as_float(ws[p] << 16);
            r[2*p+1] = ac[2*p+1] + dn * __uint_as_float(ws[p] & 0xFFFF0000u);
        }
        float* op = &out[(size_t)n * DIM + c * 8];
        const float* bp = &b[c * 8];
        float4 o0, o1;
        o0.x = dn * r[0] + bp[0]; o0.y = dn * r[1] + bp[1];
        o0.z = dn * r[2] + bp[2]; o0.w = dn * r[3] + bp[3];
        o1.x = dn * r[4] + bp[4]; o1.y = dn * r[5] + bp[5];
        o1.z = dn * r[6] + bp[6]; o1.w = dn * r[7] + bp[7];
        *(float4*)op = o0;
        *(float4*)(op + 4) = o1;
    }
}

extern "C" void kernel_launch(void* const* d_in, const int* in_sizes, int n_in,
                              void* d_out, int out_size, void* d_ws, size_t ws_size,
                              hipStream_t stream) {
    const float* W_embed = (const float*)d_in[0];
    const float* W_gcn   = (const float*)d_in[1];
    const float* b_gcn   = (const float*)d_in[2];
    const int*   edges   = (const int*)d_in[3];
    const int E = in_sizes[3] / 2;
    const int* src = edges;
    const int* dst = edges + E;

    float* out = (float*)d_out;
    char*  ws  = (char*)d_ws;
    int*    gcntp = (int*)ws;                    // NB*8*16 ints (100 KB)  @ 0
    int*    ocnt  = (int*)(ws + 0x19000);        // 1 int                  @ 100 KB
    int*    obkt  = (int*)(ws + 0x20000);        // OCAP ints (32 KB)      @ 128 KB
    ushort* wt    = (ushort*)(ws + 0x28000);     // 128x128 bf16 (32 KB)   @ 160 KB
    int*    gbkt  = (int*)(ws + 0x30000);        // NB*8*GCAPR ints (4 MB) @ 192 KB
    ushort* slot  = (ushort*)(ws + 0x500000);    // NB*256*CAP ushort (6.4MB) @ 5 MB
    int*    deg   = (int*)(ws + 0xC00000);       // N ints (200 KB)        @ 12 MB
    ushort* h16   = (ushort*)(ws + 0xD00000);    // N*D bf16 (12.8 MB)     @ 13 MB

    prep_kernel<<<17, 256, 0, stream>>>(gcntp, ocnt, W_gcn, wt);
    gemm_fill_kernel<<<GEMM_BLOCKS + FILLB, 256, 0, stream>>>(
        W_embed, wt, h16, src, dst, E, gcntp, gbkt, ocnt, obkt);
    bin_kernel<<<NB, 256, 0, stream>>>(gcntp, gbkt, ocnt, obkt, slot, deg);
    pull_kernel<<<(N_NODES + 3) / 4, 256, 0, stream>>>(deg, slot, h16, b_gcn, out);
}

// Round 16
// 66.750 us; speedup vs baseline: 1.3710x; 1.0704x over previous
//
#include <hip/hip_runtime.h>

#define N_NODES 50001
#define DIM 128
#define GEMM_BLOCKS 391                // ceil(N_NODES / 128): 4 waves x 32 rows per block
#define CAP 64                         // slot capacity per node
#define NB 196                         // buckets = dst>>8
#define FILLB 488                      // fill blocks
#define EPB 1232                       // edges per fill block (488*1232 = 601216 >= 600000)
#define BCAP 24                        // per-(block,bucket) LDS capacity (mean 6.3)
#define GCAPR 640                      // per-(bucket,replica) capacity (mean 383, +13 sigma)
#define OCAP 8192                      // overflow list capacity

typedef __attribute__((ext_vector_type(8))) short short8v;   // 8 bf16 (MFMA A/B frag)
typedef __attribute__((ext_vector_type(4))) float f32x4;     // MFMA C/D frag

__device__ __forceinline__ ushort f2bf(float f) {
    unsigned u = __float_as_uint(f);
    unsigned r = (u + 0x7FFF + ((u >> 16) & 1)) >> 16;   // round-to-nearest-even
    return (ushort)r;
}

// ---------------- prep: [zero counters | transpose W (fp32) -> wt (bf16 [n][k])] ----------
__global__ void prep_kernel(int* __restrict__ gcntp, int* __restrict__ ocnt,
                            const float* __restrict__ Wg, ushort* __restrict__ wt) {
    __shared__ float tile[32][36];
    const int t = threadIdx.x;
    if (blockIdx.x == 0) {
        for (int i = t; i < NB * 8 * 16; i += 256) gcntp[i] = 0;
        if (t == 0) *ocnt = 0;
        return;
    }
    const int b2 = blockIdx.x - 1;        // 0..15
    const int bk = b2 >> 2;               // k-tile
    const int bn = b2 & 3;                // n-tile
    {
        int k = bk * 32 + (t >> 3);
        int n = bn * 32 + (t & 7) * 4;
        float4 v = *(const float4*)&Wg[(size_t)k * DIM + n];
        tile[t >> 3][(t & 7) * 4 + 0] = v.x;
        tile[t >> 3][(t & 7) * 4 + 1] = v.y;
        tile[t >> 3][(t & 7) * 4 + 2] = v.z;
        tile[t >> 3][(t & 7) * 4 + 3] = v.w;
    }
    __syncthreads();
    {
        int n = bn * 32 + (t >> 3);
        int k = bk * 32 + (t & 7) * 4;
        ushort4 w4;
        w4.x = f2bf(tile[(t & 7) * 4 + 0][t >> 3]);
        w4.y = f2bf(tile[(t & 7) * 4 + 1][t >> 3]);
        w4.z = f2bf(tile[(t & 7) * 4 + 2][t >> 3]);
        w4.w = f2bf(tile[(t & 7) * 4 + 3][t >> 3]);
        *(ushort4*)&wt[(size_t)n * DIM + k] = w4;
    }
}

// -------- fused: [MFMA gemm, 32 rows/wave (first) | level-1: LDS bin -> parallel flush] ---
// entry = src | (dst&255)<<16 (| bucket<<24 in overflow list).
__launch_bounds__(256)
__global__ void gemm_fill_kernel(const float* __restrict__ X, const ushort* __restrict__ wt,
                                 ushort* __restrict__ h16,
                                 const int* __restrict__ src, const int* __restrict__ dst,
                                 int E, int* __restrict__ gcntp, int* __restrict__ gbkt,
                                 int* __restrict__ ocnt, int* __restrict__ obkt) {
    __shared__ int lcnt[NB];
    __shared__ int lgpos[NB];
    __shared__ int lbkt[NB * BCAP];      // ~18.4 KB (20.4 KB total LDS)
    const int bid = blockIdx.x;
    const int t   = threadIdx.x;
    if (bid >= GEMM_BLOCKS) {
        const int fid = bid - GEMM_BLOCKS;
        const int r   = bid & 7;         // ~XCD id (round-robin dispatch heuristic)
        for (int i = t; i < NB; i += 256) lcnt[i] = 0;
        __syncthreads();
        const int e0 = fid * EPB;
        const int e1 = min(e0 + EPB, E);
        for (int e = e0 + t; e < e1; e += 256) {
            int d = dst[e];
            int s = src[e];
            int b = d >> 8;
            unsigned en = (unsigned)s | ((unsigned)(d & 255) << 16);
            int pos = atomicAdd(&lcnt[b], 1);
            if (pos < BCAP) lbkt[b * BCAP + pos] = (int)en;
            else {
                int op = atomicAdd(ocnt, 1);
                if (op < OCAP) obkt[op] = (int)(en | ((unsigned)b << 24));
            }
        }
        __syncthreads();
        // flush phase A: one replica atomic per bucket, broadcast base via LDS
        if (t < NB) {
            int c = min(lcnt[t], BCAP);
            lcnt[t] = c;
            lgpos[t] = (c > 0) ? atomicAdd(&gcntp[(t * 8 + r) * 16], c) : 0;
        }
        __syncthreads();
        // flush phase B: 4 threads per bucket copy interleaved elements
#pragma unroll
        for (int rr = 0; rr < 4; ++rr) {
            int b = rr * 64 + (t >> 2);
            if (b < NB) {
                const int j    = t & 3;
                const int c    = lcnt[b];
                const int gpos = lgpos[b];
                int* gp = &gbkt[(size_t)(b * 8 + r) * GCAPR];
                for (int i = j; i < c; i += 4) {
                    int g = gpos + i;
                    if (g < GCAPR) gp[g] = lbkt[b * BCAP + i];
                    else {
                        int op = atomicAdd(ocnt, 1);
                        if (op < OCAP)
                            obkt[op] = (int)((unsigned)lbkt[b * BCAP + i] | ((unsigned)b << 24));
                    }
                }
            }
        }
        return;
    }
    // ---- GEMM branch: 128 rows per block, 32 rows per wave (two 16-row tiles) ----
    const int l    = t & 63;
    const int wave = t >> 6;
    const int m0   = bid * 128 + wave * 32;
    const int lm   = l & 15;          // A row / D col index
    const int lg   = l >> 4;          // k-group

    const int r0   = m0 + lm;         // tile-0 A row
    const int r1   = m0 + 16 + lm;    // tile-1 A row
    const bool ok0 = (r0 > 0) && (r0 < N_NODES);   // row 0 forced to zero
    const bool ok1 = (r1 > 0) && (r1 < N_NODES);
    const int koff0 = lg * 8;

    f32x4 acc[2][8];
#pragma unroll
    for (int ti = 0; ti < 2; ++ti)
#pragma unroll
        for (int ct = 0; ct < 8; ++ct) acc[ti][ct] = (f32x4){0.f, 0.f, 0.f, 0.f};

#pragma unroll
    for (int kci = 0; kci < 4; ++kci) {
        const int kc = kci * 32;
        // A frags: X[r][kc + koff0 + 0..7] fp32 -> bf16 (same (g,j)->k bijection as B)
        float4 v0 = make_float4(0.f, 0.f, 0.f, 0.f), v1 = v0, v2 = v0, v3 = v0;
        if (ok0) {
            const float* xp = &X[(size_t)r0 * DIM + kc + koff0];
            v0 = *(const float4*)xp;
            v1 = *(const float4*)(xp + 4);
        }
        if (ok1) {
            const float* xp = &X[(size_t)r1 * DIM + kc + koff0];
            v2 = *(const float4*)xp;
            v3 = *(const float4*)(xp + 4);
        }
        short8v a0, a1;
        a0[0] = (short)f2bf(v0.x); a0[1] = (short)f2bf(v0.y);
        a0[2] = (short)f2bf(v0.z); a0[3] = (short)f2bf(v0.w);
        a0[4] = (short)f2bf(v1.x); a0[5] = (short)f2bf(v1.y);
        a0[6] = (short)f2bf(v1.z); a0[7] = (short)f2bf(v1.w);
        a1[0] = (short)f2bf(v2.x); a1[1] = (short)f2bf(v2.y);
        a1[2] = (short)f2bf(v2.z); a1[3] = (short)f2bf(v2.w);
        a1[4] = (short)f2bf(v3.x); a1[5] = (short)f2bf(v3.y);
        a1[6] = (short)f2bf(v3.z); a1[7] = (short)f2bf(v3.w);
#pragma unroll
        for (int ct = 0; ct < 8; ++ct) {
            // B frag shared by both tiles: 16B vector load, cache-resident
            short8v b = *(const short8v*)&wt[(size_t)(ct * 16 + lm) * DIM + kc + koff0];
            acc[0][ct] = __builtin_amdgcn_mfma_f32_16x16x32_bf16(a0, b, acc[0][ct], 0, 0, 0);
            acc[1][ct] = __builtin_amdgcn_mfma_f32_16x16x32_bf16(a1, b, acc[1][ct], 0, 0, 0);
        }
    }

    // D: row = m0 + ti*16 + lg*4 + r, col = ct*16 + lm
#pragma unroll
    for (int ti = 0; ti < 2; ++ti) {
#pragma unroll
        for (int r = 0; r < 4; ++r) {
            int row = m0 + ti * 16 + lg * 4 + r;
            if (row < N_NODES) {
                ushort* hp = &h16[(size_t)row * DIM + lm];
#pragma unroll
                for (int ct = 0; ct < 8; ++ct) hp[ct * 16] = f2bf(acc[ti][ct][r]);
            }
        }
    }
}

// ---------------- level-2: per-bucket LDS binning -> slot rows + deg (all streaming) ------
__launch_bounds__(256)
__global__ void bin_kernel(const int* __restrict__ gcntp, const int* __restrict__ gbkt,
                           const int* __restrict__ ocnt, const int* __restrict__ obkt,
                           ushort* __restrict__ slot, int* __restrict__ deg) {
    __shared__ __align__(16) ushort lslot[256 * CAP];   // 32 KB
    __shared__ int ldeg[256];
    const int t = threadIdx.x;
    const int b = blockIdx.x;
    ldeg[t] = 0;
    __syncthreads();

    for (int r = 0; r < 8; ++r) {
        const int cnt = min(gcntp[(b * 8 + r) * 16], GCAPR);
        const int* bp = &gbkt[(size_t)(b * 8 + r) * GCAPR];
        for (int i = t; i < cnt; i += 256) {
            unsigned en = (unsigned)bp[i];
            int dlow = (en >> 16) & 255;
            int pos = atomicAdd(&ldeg[dlow], 1);
            if (pos < CAP) lslot[dlow * CAP + pos] = (ushort)(en & 0xFFFFu);
        }
    }
    const int oc = min(*ocnt, OCAP);
    for (int i = t; i < oc; i += 256) {
        unsigned en = (unsigned)obkt[i];
        if ((int)(en >> 24) == b) {
            int dlow = (en >> 16) & 255;
            int pos = atomicAdd(&ldeg[dlow], 1);
            if (pos < CAP) lslot[dlow * CAP + pos] = (ushort)(en & 0xFFFFu);
        }
    }
    __syncthreads();

    const int node = b * 256 + t;
    if (node < N_NODES) deg[node] = ldeg[t];
    // stream 32 KB of slot rows (tails beyond ldeg are never read)
    const uint4* ls4 = (const uint4*)lslot;
    uint4* gs4 = (uint4*)&slot[(size_t)b * 256 * CAP];
#pragma unroll
    for (int k = 0; k < 8; ++k) gs4[k * 256 + t] = ls4[k * 256 + t];
}

// ---------------- pull: out[n] = dis_n*(sum_e dis_s*h[s] + dis_n*h[n]) + b ----------
// One wave per node; quarter-wave (16 lanes x 16B) per edge -> 4 edges in flight.
__launch_bounds__(256)
__global__ void pull_kernel(const int* __restrict__ deg, const ushort* __restrict__ slot,
                            const ushort* __restrict__ h16,
                            const float* __restrict__ b, float* __restrict__ out) {
    const int tid  = threadIdx.x;
    const int lane = tid & 63;
    const int g    = lane >> 4;     // edge slot group 0..3
    const int c    = lane & 15;     // col slot: bf16 cols c*8 .. c*8+7
    const int n    = blockIdx.x * 4 + (tid >> 6);
    if (n >= N_NODES) return;

    const int dn_i = deg[n];
    const int end  = min(dn_i, CAP);
    const ushort* sp = &slot[(size_t)n * CAP];

    float ac[8];
#pragma unroll
    for (int j = 0; j < 8; ++j) ac[j] = 0.f;

    int e = g;
    while (e + 4 < end) {           // 2 edges per group per iter
        int s0 = sp[e];
        int s1 = sp[e + 4];
        float d0 = rsqrtf(1.0f + (float)deg[s0]);
        float d1 = rsqrtf(1.0f + (float)deg[s1]);
        uint4 u0 = *(const uint4*)&h16[(size_t)s0 * DIM + c * 8];
        uint4 u1 = *(const uint4*)&h16[(size_t)s1 * DIM + c * 8];
        const unsigned w0[4] = {u0.x, u0.y, u0.z, u0.w};
        const unsigned w1[4] = {u1.x, u1.y, u1.z, u1.w};
#pragma unroll
        for (int p = 0; p < 4; ++p) {
            ac[2*p]   += d0 * __uint_as_float(w0[p] << 16)
                       + d1 * __uint_as_float(w1[p] << 16);
            ac[2*p+1] += d0 * __uint_as_float(w0[p] & 0xFFFF0000u)
                       + d1 * __uint_as_float(w1[p] & 0xFFFF0000u);
        }
        e += 8;
    }
    while (e < end) {
        int s = sp[e];
        float d = rsqrtf(1.0f + (float)deg[s]);
        uint4 u = *(const uint4*)&h16[(size_t)s * DIM + c * 8];
        const unsigned w[4] = {u.x, u.y, u.z, u.w};
#pragma unroll
        for (int p = 0; p < 4; ++p) {
            ac[2*p]   += d * __uint_as_float(w[p] << 16);
            ac[2*p+1] += d * __uint_as_float(w[p] & 0xFFFF0000u);
        }
        e += 4;
    }

    // combine the 4 edge-slot partials (same cols in every group)
#pragma unroll
    for (int j = 0; j < 8; ++j) {
        ac[j] += __shfl_xor(ac[j], 16, 64);
        ac[j] += __shfl_xor(ac[j], 32, 64);
    }

    if (g == 0) {
        const float dn = rsqrtf(1.0f + (float)dn_i);
        uint4 us = *(const uint4*)&h16[(size_t)n * DIM + c * 8];   // self row (bf16)
        const unsigned ws[4] = {us.x, us.y, us.z, us.w};
        float r[8];
#pragma unroll
        for (int p = 0; p < 4; ++p) {
            r[2*p]   = ac[2*p]   + dn * __uint_as_float(ws[p] << 16);
            r[2*p+1] = ac[2*p+1] + dn * __uint_as_float(ws[p] & 0xFFFF0000u);
        }
        float* op = &out[(size_t)n * DIM + c * 8];
        const float* bp = &b[c * 8];
        float4 o0, o1;
        o0.x = dn * r[0] + bp[0]; o0.y = dn * r[1] + bp[1];
        o0.z = dn * r[2] + bp[2]; o0.w = dn * r[3] + bp[3];
        o1.x = dn * r[4] + bp[4]; o1.y = dn * r[5] + bp[5];
        o1.z = dn * r[6] + bp[6]; o1.w = dn * r[7] + bp[7];
        *(float4*)op = o0;
        *(float4*)(op + 4) = o1;
    }
}

extern "C" void kernel_launch(void* const* d_in, const int* in_sizes, int n_in,
                              void* d_out, int out_size, void* d_ws, size_t ws_size,
                              hipStream_t stream) {
    const float* W_embed = (const float*)d_in[0];
    const float* W_gcn   = (const float*)d_in[1];
    const float* b_gcn   = (const float*)d_in[2];
    const int*   edges   = (const int*)d_in[3];
    const int E = in_sizes[3] / 2;
    const int* src = edges;
    const int* dst = edges + E;

    float* out = (float*)d_out;
    char*  ws  = (char*)d_ws;
    int*    gcntp = (int*)ws;                    // NB*8*16 ints (100 KB)  @ 0
    int*    ocnt  = (int*)(ws + 0x19000);        // 1 int                  @ 100 KB
    int*    obkt  = (int*)(ws + 0x20000);        // OCAP ints (32 KB)      @ 128 KB
    ushort* wt    = (ushort*)(ws + 0x28000);     // 128x128 bf16 (32 KB)   @ 160 KB
    int*    gbkt  = (int*)(ws + 0x30000);        // NB*8*GCAPR ints (4 MB) @ 192 KB
    ushort* slot  = (ushort*)(ws + 0x500000);    // NB*256*CAP ushort (6.4MB) @ 5 MB
    int*    deg   = (int*)(ws + 0xC00000);       // N ints (200 KB)        @ 12 MB
    ushort* h16   = (ushort*)(ws + 0xD00000);    // N*D bf16 (12.8 MB)     @ 13 MB

    prep_kernel<<<17, 256, 0, stream>>>(gcntp, ocnt, W_gcn, wt);
    gemm_fill_kernel<<<GEMM_BLOCKS + FILLB, 256, 0, stream>>>(
        W_embed, wt, h16, src, dst, E, gcntp, gbkt, ocnt, obkt);
    bin_kernel<<<NB, 256, 0, stream>>>(gcntp, gbkt, ocnt, obkt, slot, deg);
    pull_kernel<<<(N_NODES + 3) / 4, 256, 0, stream>>>(deg, slot, h16, b_gcn, out);
}

// Round 17
// 63.363 us; speedup vs baseline: 1.4443x; 1.0534x over previous
//
#include <hip/hip_runtime.h>

#define N_NODES 50001
#define DIM 128
#define GEMM_BLOCKS 196                // ceil(N_NODES / 256): 4 waves x 64 rows per block
#define CAP 64                         // slot capacity per node
#define NB 196                         // buckets = dst>>8
#define FILLB 488                      // fill blocks
#define EPB 1232                       // edges per fill block (488*1232 = 601216 >= 600000)
#define BCAP 24                        // per-(block,bucket) LDS capacity (mean 6.3)
#define GCAPR 640                      // per-(bucket,replica) capacity (mean 383, +13 sigma)
#define OCAP 8192                      // overflow list capacity

typedef __attribute__((ext_vector_type(8))) short short8v;   // 8 bf16 (MFMA A/B frag)
typedef __attribute__((ext_vector_type(4))) float f32x4;     // MFMA C/D frag

__device__ __forceinline__ ushort f2bf(float f) {
    unsigned u = __float_as_uint(f);
    unsigned r = (u + 0x7FFF + ((u >> 16) & 1)) >> 16;   // round-to-nearest-even
    return (ushort)r;
}

// ---------------- prep: [zero counters | transpose W (fp32) -> wt (bf16 [n][k])] ----------
__global__ void prep_kernel(int* __restrict__ gcntp, int* __restrict__ ocnt,
                            const float* __restrict__ Wg, ushort* __restrict__ wt) {
    __shared__ float tile[32][36];
    const int t = threadIdx.x;
    if (blockIdx.x == 0) {
        for (int i = t; i < NB * 8 * 16; i += 256) gcntp[i] = 0;
        if (t == 0) *ocnt = 0;
        return;
    }
    const int b2 = blockIdx.x - 1;        // 0..15
    const int bk = b2 >> 2;               // k-tile
    const int bn = b2 & 3;                // n-tile
    {
        int k = bk * 32 + (t >> 3);
        int n = bn * 32 + (t & 7) * 4;
        float4 v = *(const float4*)&Wg[(size_t)k * DIM + n];
        tile[t >> 3][(t & 7) * 4 + 0] = v.x;
        tile[t >> 3][(t & 7) * 4 + 1] = v.y;
        tile[t >> 3][(t & 7) * 4 + 2] = v.z;
        tile[t >> 3][(t & 7) * 4 + 3] = v.w;
    }
    __syncthreads();
    {
        int n = bn * 32 + (t >> 3);
        int k = bk * 32 + (t & 7) * 4;
        ushort4 w4;
        w4.x = f2bf(tile[(t & 7) * 4 + 0][t >> 3]);
        w4.y = f2bf(tile[(t & 7) * 4 + 1][t >> 3]);
        w4.z = f2bf(tile[(t & 7) * 4 + 2][t >> 3]);
        w4.w = f2bf(tile[(t & 7) * 4 + 3][t >> 3]);
        *(ushort4*)&wt[(size_t)n * DIM + k] = w4;
    }
}

// -------- fused: [MFMA gemm, 64 rows/wave (first) | level-1: LDS bin -> parallel flush] ---
// entry = src | (dst&255)<<16 (| bucket<<24 in overflow list).
__launch_bounds__(256)
__global__ void gemm_fill_kernel(const float* __restrict__ X, const ushort* __restrict__ wt,
                                 ushort* __restrict__ h16,
                                 const int* __restrict__ src, const int* __restrict__ dst,
                                 int E, int* __restrict__ gcntp, int* __restrict__ gbkt,
                                 int* __restrict__ ocnt, int* __restrict__ obkt) {
    __shared__ int lcnt[NB];
    __shared__ int lgpos[NB];
    __shared__ int lbkt[NB * BCAP];      // ~18.4 KB (20.4 KB total LDS)
    const int bid = blockIdx.x;
    const int t   = threadIdx.x;
    if (bid >= GEMM_BLOCKS) {
        const int fid = bid - GEMM_BLOCKS;
        const int r   = bid & 7;         // ~XCD id (round-robin dispatch heuristic)
        for (int i = t; i < NB; i += 256) lcnt[i] = 0;
        __syncthreads();
        const int e0 = fid * EPB;
        const int e1 = min(e0 + EPB, E);
        for (int e = e0 + t; e < e1; e += 256) {
            int d = dst[e];
            int s = src[e];
            int b = d >> 8;
            unsigned en = (unsigned)s | ((unsigned)(d & 255) << 16);
            int pos = atomicAdd(&lcnt[b], 1);
            if (pos < BCAP) lbkt[b * BCAP + pos] = (int)en;
            else {
                int op = atomicAdd(ocnt, 1);
                if (op < OCAP) obkt[op] = (int)(en | ((unsigned)b << 24));
            }
        }
        __syncthreads();
        // flush phase A: one replica atomic per bucket, broadcast base via LDS
        if (t < NB) {
            int c = min(lcnt[t], BCAP);
            lcnt[t] = c;
            lgpos[t] = (c > 0) ? atomicAdd(&gcntp[(t * 8 + r) * 16], c) : 0;
        }
        __syncthreads();
        // flush phase B: 4 threads per bucket copy interleaved elements
#pragma unroll
        for (int rr = 0; rr < 4; ++rr) {
            int b = rr * 64 + (t >> 2);
            if (b < NB) {
                const int j    = t & 3;
                const int c    = lcnt[b];
                const int gpos = lgpos[b];
                int* gp = &gbkt[(size_t)(b * 8 + r) * GCAPR];
                for (int i = j; i < c; i += 4) {
                    int g = gpos + i;
                    if (g < GCAPR) gp[g] = lbkt[b * BCAP + i];
                    else {
                        int op = atomicAdd(ocnt, 1);
                        if (op < OCAP)
                            obkt[op] = (int)((unsigned)lbkt[b * BCAP + i] | ((unsigned)b << 24));
                    }
                }
            }
        }
        return;
    }
    // ---- GEMM branch: 256 rows per block, 64 rows per wave (four 16-row tiles) ----
    const int l    = t & 63;
    const int wave = t >> 6;
    const int m0   = bid * 256 + wave * 64;
    const int lm   = l & 15;          // A row / D col index
    const int lg   = l >> 4;          // k-group
    const int koff0 = lg * 8;

    f32x4 acc[4][8];
#pragma unroll
    for (int ti = 0; ti < 4; ++ti)
#pragma unroll
        for (int ct = 0; ct < 8; ++ct) acc[ti][ct] = (f32x4){0.f, 0.f, 0.f, 0.f};

#pragma unroll
    for (int kci = 0; kci < 4; ++kci) {
        const int kc = kci * 32;
        short8v a[4];
#pragma unroll
        for (int ti = 0; ti < 4; ++ti) {
            const int rr = m0 + ti * 16 + lm;
            float4 v0 = make_float4(0.f, 0.f, 0.f, 0.f), v1 = v0;
            if ((rr > 0) && (rr < N_NODES)) {      // row 0 forced to zero
                const float* xp = &X[(size_t)rr * DIM + kc + koff0];
                v0 = *(const float4*)xp;
                v1 = *(const float4*)(xp + 4);
            }
            a[ti][0] = (short)f2bf(v0.x); a[ti][1] = (short)f2bf(v0.y);
            a[ti][2] = (short)f2bf(v0.z); a[ti][3] = (short)f2bf(v0.w);
            a[ti][4] = (short)f2bf(v1.x); a[ti][5] = (short)f2bf(v1.y);
            a[ti][6] = (short)f2bf(v1.z); a[ti][7] = (short)f2bf(v1.w);
        }
#pragma unroll
        for (int ct = 0; ct < 8; ++ct) {
            // B frag shared by all four tiles: 16B vector load, cache-resident
            short8v b = *(const short8v*)&wt[(size_t)(ct * 16 + lm) * DIM + kc + koff0];
            acc[0][ct] = __builtin_amdgcn_mfma_f32_16x16x32_bf16(a[0], b, acc[0][ct], 0, 0, 0);
            acc[1][ct] = __builtin_amdgcn_mfma_f32_16x16x32_bf16(a[1], b, acc[1][ct], 0, 0, 0);
            acc[2][ct] = __builtin_amdgcn_mfma_f32_16x16x32_bf16(a[2], b, acc[2][ct], 0, 0, 0);
            acc[3][ct] = __builtin_amdgcn_mfma_f32_16x16x32_bf16(a[3], b, acc[3][ct], 0, 0, 0);
        }
    }

    // D: row = m0 + ti*16 + lg*4 + r, col = ct*16 + lm
#pragma unroll
    for (int ti = 0; ti < 4; ++ti) {
#pragma unroll
        for (int r = 0; r < 4; ++r) {
            int row = m0 + ti * 16 + lg * 4 + r;
            if (row < N_NODES) {
                ushort* hp = &h16[(size_t)row * DIM + lm];
#pragma unroll
                for (int ct = 0; ct < 8; ++ct) hp[ct * 16] = f2bf(acc[ti][ct][r]);
            }
        }
    }
}

// ---------------- level-2: per-bucket LDS binning -> slot rows + deg (all streaming) ------
__launch_bounds__(256)
__global__ void bin_kernel(const int* __restrict__ gcntp, const int* __restrict__ gbkt,
                           const int* __restrict__ ocnt, const int* __restrict__ obkt,
                           ushort* __restrict__ slot, int* __restrict__ deg) {
    __shared__ __align__(16) ushort lslot[256 * CAP];   // 32 KB
    __shared__ int ldeg[256];
    const int t = threadIdx.x;
    const int b = blockIdx.x;
    ldeg[t] = 0;
    __syncthreads();

    for (int r = 0; r < 8; ++r) {
        const int cnt = min(gcntp[(b * 8 + r) * 16], GCAPR);
        const int* bp = &gbkt[(size_t)(b * 8 + r) * GCAPR];
        for (int i = t; i < cnt; i += 256) {
            unsigned en = (unsigned)bp[i];
            int dlow = (en >> 16) & 255;
            int pos = atomicAdd(&ldeg[dlow], 1);
            if (pos < CAP) lslot[dlow * CAP + pos] = (ushort)(en & 0xFFFFu);
        }
    }
    const int oc = min(*ocnt, OCAP);
    for (int i = t; i < oc; i += 256) {
        unsigned en = (unsigned)obkt[i];
        if ((int)(en >> 24) == b) {
            int dlow = (en >> 16) & 255;
            int pos = atomicAdd(&ldeg[dlow], 1);
            if (pos < CAP) lslot[dlow * CAP + pos] = (ushort)(en & 0xFFFFu);
        }
    }
    __syncthreads();

    const int node = b * 256 + t;
    if (node < N_NODES) deg[node] = ldeg[t];
    // stream 32 KB of slot rows (tails beyond ldeg are never read)
    const uint4* ls4 = (const uint4*)lslot;
    uint4* gs4 = (uint4*)&slot[(size_t)b * 256 * CAP];
#pragma unroll
    for (int k = 0; k < 8; ++k) gs4[k * 256 + t] = ls4[k * 256 + t];
}

// ---------------- pull: out[n] = dis_n*(sum_e dis_s*h[s] + dis_n*h[n]) + b ----------
// One wave per node; quarter-wave (16 lanes x 16B) per edge -> 4 edges in flight.
__launch_bounds__(256)
__global__ void pull_kernel(const int* __restrict__ deg, const ushort* __restrict__ slot,
                            const ushort* __restrict__ h16,
                            const float* __restrict__ b, float* __restrict__ out) {
    const int tid  = threadIdx.x;
    const int lane = tid & 63;
    const int g    = lane >> 4;     // edge slot group 0..3
    const int c    = lane & 15;     // col slot: bf16 cols c*8 .. c*8+7
    const int n    = blockIdx.x * 4 + (tid >> 6);
    if (n >= N_NODES) return;

    const int dn_i = deg[n];
    const int end  = min(dn_i, CAP);
    const ushort* sp = &slot[(size_t)n * CAP];

    float ac[8];
#pragma unroll
    for (int j = 0; j < 8; ++j) ac[j] = 0.f;

    int e = g;
    while (e + 4 < end) {           // 2 edges per group per iter
        int s0 = sp[e];
        int s1 = sp[e + 4];
        float d0 = rsqrtf(1.0f + (float)deg[s0]);
        float d1 = rsqrtf(1.0f + (float)deg[s1]);
        uint4 u0 = *(const uint4*)&h16[(size_t)s0 * DIM + c * 8];
        uint4 u1 = *(const uint4*)&h16[(size_t)s1 * DIM + c * 8];
        const unsigned w0[4] = {u0.x, u0.y, u0.z, u0.w};
        const unsigned w1[4] = {u1.x, u1.y, u1.z, u1.w};
#pragma unroll
        for (int p = 0; p < 4; ++p) {
            ac[2*p]   += d0 * __uint_as_float(w0[p] << 16)
                       + d1 * __uint_as_float(w1[p] << 16);
            ac[2*p+1] += d0 * __uint_as_float(w0[p] & 0xFFFF0000u)
                       + d1 * __uint_as_float(w1[p] & 0xFFFF0000u);
        }
        e += 8;
    }
    while (e < end) {
        int s = sp[e];
        float d = rsqrtf(1.0f + (float)deg[s]);
        uint4 u = *(const uint4*)&h16[(size_t)s * DIM + c * 8];
        const unsigned w[4] = {u.x, u.y, u.z, u.w};
#pragma unroll
        for (int p = 0; p < 4; ++p) {
            ac[2*p]   += d * __uint_as_float(w[p] << 16);
            ac[2*p+1] += d * __uint_as_float(w[p] & 0xFFFF0000u);
        }
        e += 4;
    }

    // combine the 4 edge-slot partials (same cols in every group)
#pragma unroll
    for (int j = 0; j < 8; ++j) {
        ac[j] += __shfl_xor(ac[j], 16, 64);
        ac[j] += __shfl_xor(ac[j], 32, 64);
    }

    if (g == 0) {
        const float dn = rsqrtf(1.0f + (float)dn_i);
        uint4 us = *(const uint4*)&h16[(size_t)n * DIM + c * 8];   // self row (bf16)
        const unsigned ws[4] = {us.x, us.y, us.z, us.w};
        float r[8];
#pragma unroll
        for (int p = 0; p < 4; ++p) {
            r[2*p]   = ac[2*p]   + dn * __uint_as_float(ws[p] << 16);
            r[2*p+1] = ac[2*p+1] + dn * __uint_as_float(ws[p] & 0xFFFF0000u);
        }
        float* op = &out[(size_t)n * DIM + c * 8];
        const float* bp = &b[c * 8];
        float4 o0, o1;
        o0.x = dn * r[0] + bp[0]; o0.y = dn * r[1] + bp[1];
        o0.z = dn * r[2] + bp[2]; o0.w = dn * r[3] + bp[3];
        o1.x = dn * r[4] + bp[4]; o1.y = dn * r[5] + bp[5];
        o1.z = dn * r[6] + bp[6]; o1.w = dn * r[7] + bp[7];
        *(float4*)op = o0;
        *(float4*)(op + 4) = o1;
    }
}

extern "C" void kernel_launch(void* const* d_in, const int* in_sizes, int n_in,
                              void* d_out, int out_size, void* d_ws, size_t ws_size,
                              hipStream_t stream) {
    const float* W_embed = (const float*)d_in[0];
    const float* W_gcn   = (const float*)d_in[1];
    const float* b_gcn   = (const float*)d_in[2];
    const int*   edges   = (const int*)d_in[3];
    const int E = in_sizes[3] / 2;
    const int* src = edges;
    const int* dst = edges + E;

    float* out = (float*)d_out;
    char*  ws  = (char*)d_ws;
    int*    gcntp = (int*)ws;                    // NB*8*16 ints (100 KB)  @ 0
    int*    ocnt  = (int*)(ws + 0x19000);        // 1 int                  @ 100 KB
    int*    obkt  = (int*)(ws + 0x20000);        // OCAP ints (32 KB)      @ 128 KB
    ushort* wt    = (ushort*)(ws + 0x28000);     // 128x128 bf16 (32 KB)   @ 160 KB
    int*    gbkt  = (int*)(ws + 0x30000);        // NB*8*GCAPR ints (4 MB) @ 192 KB
    ushort* slot  = (ushort*)(ws + 0x500000);    // NB*256*CAP ushort (6.4MB) @ 5 MB
    int*    deg   = (int*)(ws + 0xC00000);       // N ints (200 KB)        @ 12 MB
    ushort* h16   = (ushort*)(ws + 0xD00000);    // N*D bf16 (12.8 MB)     @ 13 MB

    prep_kernel<<<17, 256, 0, stream>>>(gcntp, ocnt, W_gcn, wt);
    gemm_fill_kernel<<<GEMM_BLOCKS + FILLB, 256, 0, stream>>>(
        W_embed, wt, h16, src, dst, E, gcntp, gbkt, ocnt, obkt);
    bin_kernel<<<NB, 256, 0, stream>>>(gcntp, gbkt, ocnt, obkt, slot, deg);
    pull_kernel<<<(N_NODES + 3) / 4, 256, 0, stream>>>(deg, slot, h16, b_gcn, out);
}